// Round 5
// baseline (441.014 us; speedup 1.0000x reference)
//
#include <hip/hip_runtime.h>
#include <hip/hip_bf16.h>
#include <cstdint>
#include <cstddef>

#define HD_B   4
#define SEQ    4096
#define CDIM   768
#define HEADS  12
#define HDIM   64
#define MROWS  (HD_B * SEQ)     // 16384
#define QSCALE 0.125f
#define EPSV   1e-6f

typedef __attribute__((ext_vector_type(8))) short  short8v;  // 8 x bf16
typedef __attribute__((ext_vector_type(4))) float  f32x4;

__device__ __forceinline__ unsigned short f2b(float f) {
    unsigned int u = __float_as_uint(f);
    u += 0x7FFFu + ((u >> 16) & 1u);   // RNE
    return (unsigned short)(u >> 16);
}
__device__ __forceinline__ float b2f(unsigned short b) {
    return __uint_as_float(((unsigned int)b) << 16);
}
__device__ __forceinline__ float phi_f(float x) {  // elu(x)+1
    return x > 0.f ? x + 1.f : __expf(x);
}

// ---------------------------------------------------------------- fused convert
// dst contiguous: [xq16 | xkv16 | Wq | Wk | Wv | Wp]  (all bf16)
#define N4X 3145728     // MROWS*CDIM/4
#define N4W 147456      // CDIM*CDIM/4
__global__ void cvt_multi(const float* __restrict__ xq, const float* __restrict__ xkv,
                          const float* __restrict__ wq, const float* __restrict__ wk,
                          const float* __restrict__ wv, const float* __restrict__ wp,
                          unsigned short* __restrict__ dst) {
    const int i = blockIdx.x * 256 + threadIdx.x;
    const float* src;
    int off;
    if (i < N4X)            { src = xq;  off = 0; }
    else if (i < 2 * N4X)   { src = xkv; off = N4X; }
    else {
        const int wi = (i - 2 * N4X) / N4W;
        src = (wi == 0) ? wq : (wi == 1) ? wk : (wi == 2) ? wv : wp;
        off = 2 * N4X + wi * N4W;
    }
    float4 v = reinterpret_cast<const float4*>(src)[i - off];
    ushort4 o;
    o.x = f2b(v.x); o.y = f2b(v.y); o.z = f2b(v.z); o.w = f2b(v.w);
    reinterpret_cast<ushort4*>(dst)[i] = o;
}

// ---------------------------------------------------------------- T14 reg-staged GEMM
// 128x128 tile, BK=64, single 32 KB LDS buffer, next-tile global loads issued to
// REGISTERS before compute (latency hides under ds_read+MFMA), swizzled ds_write.
// KIND 0: fused Q|K|V projections, 2304 blocks (18 col-panels x 128 row-panels).
//         mode = colp/6: 0 -> A=xq16,B=Wq, out_q = phi(QSCALE*(acc+b0))
//                        1 -> A=xkv16,B=Wk, out_k = phi(acc+b1)
//                        2 -> A=xkv16,B=Wv, out_v = acc+b2
// KIND 1: output projection, 768 blocks, A=attn16, B=Wp, out_f = acc+b0 (fp32)
template <int KIND>
__global__ __launch_bounds__(256) void gemm_t14(
    const unsigned short* __restrict__ Aq,
    const unsigned short* __restrict__ Akv,
    const unsigned short* __restrict__ Wb,
    const float* __restrict__ b0, const float* __restrict__ b1,
    const float* __restrict__ b2,
    unsigned short* __restrict__ out_q, unsigned short* __restrict__ out_k,
    unsigned short* __restrict__ out_v, float* __restrict__ out_f)
{
    constexpr int K  = CDIM;                 // 768
    constexpr int NC = (KIND == 0) ? 18 : 6;
    constexpr int T  = NC * 128;
    constexpr int NT = K / 64;               // 12

    __shared__ __align__(16) char smem[32768];
    char* As = smem;
    char* Bs = smem + 16384;

    const int tid  = threadIdx.x;
    const int lane = tid & 63;
    const int w    = tid >> 6;
    const int wr   = w >> 1, wc = w & 1;

    // bijective XCD swizzle (T % 8 == 0), cols fast within each XCD band
    const int bid  = blockIdx.x;
    const int s    = (bid & 7) * (T >> 3) + (bid >> 3);
    const int colp = s % NC;
    const int rowp = s / NC;
    const int brow = rowp * 128;
    const int mode = (KIND == 0) ? (colp / 6) : 3;
    const int bcol = (KIND == 0) ? (colp % 6) * 128 : colp * 128;

    const unsigned short* A16 = (KIND == 0) ? (mode == 0 ? Aq : Akv) : Aq;
    const unsigned short* Bp  = Wb + ((KIND == 0) ? (size_t)mode * (K * K) : 0);

    // staging geometry: linear global loads (16 B/lane), swizzled LDS writes
    const int r8 = lane >> 3;                 // 0..7
    const int c8 = (lane & 7) << 3;           // element col 0..56
    const int wbyte = ((lane & 7) ^ r8) << 4; // swizzled 16B-chunk byte offset
    // frag-read geometry
    const int fr  = lane & 15;
    const int hi4 = lane >> 4;

    const unsigned short* aB = A16 + (size_t)(brow + w * 32 + r8) * K + c8;
    const unsigned short* bB = Bp  + (size_t)(bcol + w * 32 + r8) * K + c8;

    f32x4 acc[4][4];
#pragma unroll
    for (int i = 0; i < 4; ++i)
#pragma unroll
        for (int j = 0; j < 4; ++j)
            acc[i][j] = (f32x4){0.f, 0.f, 0.f, 0.f};

    int4 rA[4], rB[4];

#define GLOAD(k0) do {                                                      \
    _Pragma("unroll")                                                       \
    for (int g = 0; g < 4; ++g) {                                           \
        rA[g] = *(const int4*)(aB + (size_t)(g * 8) * K + (k0));            \
        rB[g] = *(const int4*)(bB + (size_t)(g * 8) * K + (k0));            \
    } } while (0)

#define SWRITE() do {                                                       \
    _Pragma("unroll")                                                       \
    for (int g = 0; g < 4; ++g) {                                           \
        const int rowl = w * 32 + g * 8 + r8;                               \
        *(int4*)(As + rowl * 128 + wbyte) = rA[g];                          \
        *(int4*)(Bs + rowl * 128 + wbyte) = rB[g];                          \
    } } while (0)

    auto compute = [&]() {
        short8v a[4][2];
#pragma unroll
        for (int i = 0; i < 4; ++i) {
            const int row = wr * 64 + i * 16 + fr;
#pragma unroll
            for (int ks = 0; ks < 2; ++ks)
                a[i][ks] = *(const short8v*)(As + row * 128 +
                              ((((ks << 2) + hi4) ^ (row & 7)) << 4));
        }
#pragma unroll
        for (int j = 0; j < 4; ++j) {
            const int row = wc * 64 + j * 16 + fr;
            short8v bb0 = *(const short8v*)(Bs + row * 128 + ((hi4 ^ (row & 7)) << 4));
            short8v bb1 = *(const short8v*)(Bs + row * 128 + (((4 + hi4) ^ (row & 7)) << 4));
#pragma unroll
            for (int i = 0; i < 4; ++i) {
                acc[i][j] = __builtin_amdgcn_mfma_f32_16x16x32_bf16(a[i][0], bb0, acc[i][j], 0, 0, 0);
                acc[i][j] = __builtin_amdgcn_mfma_f32_16x16x32_bf16(a[i][1], bb1, acc[i][j], 0, 0, 0);
            }
        }
    };

    // prologue
    GLOAD(0);
    SWRITE();
    __syncthreads();

    for (int t = 0; t < NT; ++t) {
        if (t < NT - 1) GLOAD((t + 1) * 64);       // issue early -> hides under compute
        __builtin_amdgcn_sched_barrier(0);          // pin loads before compute
        compute();
        __syncthreads();                            // all waves done reading LDS
        if (t < NT - 1) {
            SWRITE();                               // compiler waits vmcnt at consume
            __syncthreads();                        // writes visible
        }
    }
#undef GLOAD
#undef SWRITE

    // ---------------- epilogue: wave-private LDS transpose, vectorized stores
    float* ep = (float*)(void*)smem + w * (16 * 68);
    const int rr = lane >> 2;
    const int cb = (lane & 3) * 4;
    const float* bptr = (KIND == 1) ? b0 : (mode == 0 ? b0 : (mode == 1 ? b1 : b2));
    unsigned short* o16 = (KIND == 0)
        ? (mode == 0 ? out_q : (mode == 1 ? out_k : out_v)) : nullptr;

    float4 bb[4];
#pragma unroll
    for (int q = 0; q < 4; ++q)
        bb[q] = *(const float4*)&bptr[bcol + wc * 64 + q * 16 + cb];

#pragma unroll
    for (int i = 0; i < 4; ++i) {
#pragma unroll
        for (int j = 0; j < 4; ++j)
#pragma unroll
            for (int r = 0; r < 4; ++r)
                ep[(hi4 * 4 + r) * 68 + j * 16 + fr] = acc[i][j][r];
#pragma unroll
        for (int q = 0; q < 4; ++q) {
            const int cc = q * 16 + cb;
            f32x4 v = *(const f32x4*)&ep[rr * 68 + cc];
            const int rg = brow + wr * 64 + i * 16 + rr;
            const int cg = bcol + wc * 64 + cc;
            const float4 bq = bb[q];
            if (KIND == 1) {
                float4 ov;
                ov.x = v[0] + bq.x; ov.y = v[1] + bq.y;
                ov.z = v[2] + bq.z; ov.w = v[3] + bq.w;
                *(float4*)(out_f + (size_t)rg * 768 + cg) = ov;
            } else {
                ushort4 ov;
                if (mode == 0) {
                    ov.x = f2b(phi_f((v[0] + bq.x) * QSCALE));
                    ov.y = f2b(phi_f((v[1] + bq.y) * QSCALE));
                    ov.z = f2b(phi_f((v[2] + bq.z) * QSCALE));
                    ov.w = f2b(phi_f((v[3] + bq.w) * QSCALE));
                } else if (mode == 1) {
                    ov.x = f2b(phi_f(v[0] + bq.x));
                    ov.y = f2b(phi_f(v[1] + bq.y));
                    ov.z = f2b(phi_f(v[2] + bq.z));
                    ov.w = f2b(phi_f(v[3] + bq.w));
                } else {
                    ov.x = f2b(v[0] + bq.x);
                    ov.y = f2b(v[1] + bq.y);
                    ov.z = f2b(v[2] + bq.z);
                    ov.w = f2b(v[3] + bq.w);
                }
                *(ushort4*)(o16 + (size_t)rg * 768 + cg) = ov;
            }
        }
    }
}

// ---------------------------------------------------------------- KV state
#define KVCH   128
#define KVITER 2
#define NCHUNK 16   // SEQ / (KVCH*KVITER)

__global__ __launch_bounds__(256) void kv_part(
    const unsigned short* __restrict__ kphi,
    const unsigned short* __restrict__ vmat,
    float* __restrict__ part)
{
    const int bh = blockIdx.y;
    const int b  = bh / HEADS, h = bh % HEADS;
    const int c  = blockIdx.x;
    __shared__ float Kl[KVCH][HDIM];
    __shared__ float Vl[KVCH][HDIM];
    const int t  = threadIdx.x;
    const int i  = t >> 2;
    const int jb = t & 3;

    float acc[16];
#pragma unroll
    for (int jj = 0; jj < 16; ++jj) acc[jj] = 0.f;
    float ksum = 0.f;

    for (int it = 0; it < KVITER; ++it) {
        const size_t rbase = (size_t)b * SEQ + (size_t)c * (KVCH * KVITER) + it * KVCH;
        __syncthreads();
        for (int l = 0; l < KVCH / 32; ++l) {
            int row = l * 32 + (t >> 3);
            int col = (t & 7) << 3;
            const size_t g = (rbase + row) * CDIM + h * HDIM + col;
            int4 kk = *(const int4*)(kphi + g);
            int4 vv = *(const int4*)(vmat + g);
            const unsigned short* kp = (const unsigned short*)&kk;
            const unsigned short* vp = (const unsigned short*)&vv;
#pragma unroll
            for (int q = 0; q < 8; ++q) {
                Kl[row][col + q] = b2f(kp[q]);
                Vl[row][col + q] = b2f(vp[q]);
            }
        }
        __syncthreads();
        for (int n = 0; n < KVCH; ++n) {
            float kf = Kl[n][i];
            const float4* vr = (const float4*)&Vl[n][jb * 16];
            float4 v0 = vr[0], v1 = vr[1], v2 = vr[2], v3 = vr[3];
            acc[0]  += kf * v0.x; acc[1]  += kf * v0.y; acc[2]  += kf * v0.z; acc[3]  += kf * v0.w;
            acc[4]  += kf * v1.x; acc[5]  += kf * v1.y; acc[6]  += kf * v1.z; acc[7]  += kf * v1.w;
            acc[8]  += kf * v2.x; acc[9]  += kf * v2.y; acc[10] += kf * v2.z; acc[11] += kf * v2.w;
            acc[12] += kf * v3.x; acc[13] += kf * v3.y; acc[14] += kf * v3.z; acc[15] += kf * v3.w;
            ksum += kf;
        }
    }
    float* op = part + ((size_t)c * 48 + bh) * 4160;
#pragma unroll
    for (int jj = 0; jj < 16; ++jj) op[i * 64 + jb * 16 + jj] = acc[jj];
    if (jb == 0) op[4096 + i] = ksum;
}

__global__ void kv_finalize(const float* __restrict__ part, float* __restrict__ kv) {
    int idx = blockIdx.x * 256 + threadIdx.x;
    if (idx >= 48 * 4160) return;
    float s = 0.f;
    for (int c = 0; c < NCHUNK; ++c) s += part[(size_t)c * 48 * 4160 + idx];
    kv[idx] = s;
}

// ---------------------------------------------------------------- apply
__global__ __launch_bounds__(256) void attn_apply(
    const unsigned short* __restrict__ qphi,
    const float* __restrict__ kv,
    unsigned short* __restrict__ attn)
{
    const int h  = blockIdx.y;
    const int m0 = blockIdx.x * 64;
    const int b  = m0 >> 12;
    const int bh = b * HEADS + h;
    __shared__ float kvs[HDIM][HDIM];
    __shared__ float ksums[HDIM];
    __shared__ unsigned short ql[64][HDIM];
    const int t = threadIdx.x;
    const float* kvp = kv + (size_t)bh * 4160;
#pragma unroll
    for (int it = 0; it < 4; ++it) {
        int e = it * 1024 + t * 4;
        *(float4*)&kvs[e >> 6][e & 63] = *(const float4*)&kvp[e];
    }
    if (t < 64) ksums[t] = kvp[4096 + t];
#pragma unroll
    for (int it = 0; it < 2; ++it) {
        int row = it * 32 + (t >> 3);
        int col = (t & 7) << 3;
        *(int4*)&ql[row][col] =
            *(const int4*)(qphi + (size_t)(m0 + row) * CDIM + h * HDIM + col);
    }
    __syncthreads();

    const int r  = t >> 2;
    const int jb = t & 3;
    float acc[16];
#pragma unroll
    for (int jj = 0; jj < 16; ++jj) acc[jj] = 0.f;
    float z = 0.f;
    for (int q8 = 0; q8 < 8; ++q8) {
        short8v qv = *(const short8v*)&ql[r][q8 * 8];
#pragma unroll
        for (int dd = 0; dd < 8; ++dd) {
            float qd = b2f((unsigned short)qv[dd]);
            int d = q8 * 8 + dd;
            const float4* kr = (const float4*)&kvs[d][jb * 16];
            float4 k0 = kr[0], k1 = kr[1], k2 = kr[2], k3 = kr[3];
            acc[0]  += qd * k0.x; acc[1]  += qd * k0.y; acc[2]  += qd * k0.z; acc[3]  += qd * k0.w;
            acc[4]  += qd * k1.x; acc[5]  += qd * k1.y; acc[6]  += qd * k1.z; acc[7]  += qd * k1.w;
            acc[8]  += qd * k2.x; acc[9]  += qd * k2.y; acc[10] += qd * k2.z; acc[11] += qd * k2.w;
            acc[12] += qd * k3.x; acc[13] += qd * k3.y; acc[14] += qd * k3.z; acc[15] += qd * k3.w;
            z += qd * ksums[d];
        }
    }
    const float inv = 1.f / (z + EPSV);
    unsigned short* op = attn + (size_t)(m0 + r) * CDIM + h * HDIM + jb * 16;
#pragma unroll
    for (int jj = 0; jj < 16; ++jj) op[jj] = f2b(acc[jj] * inv);
}

// ---------------------------------------------------------------- launch
extern "C" void kernel_launch(void* const* d_in, const int* in_sizes, int n_in,
                              void* d_out, int out_size, void* d_ws, size_t ws_size,
                              hipStream_t stream)
{
    const float* x_q  = (const float*)d_in[0];
    const float* x_kv = (const float*)d_in[1];
    const float* Wq   = (const float*)d_in[2];
    const float* bq   = (const float*)d_in[3];
    const float* Wk   = (const float*)d_in[4];
    const float* bk   = (const float*)d_in[5];
    const float* Wv   = (const float*)d_in[6];
    const float* bv   = (const float*)d_in[7];
    const float* Wp   = (const float*)d_in[8];
    const float* bp   = (const float*)d_in[9];
    float* out = (float*)d_out;

    char* ws = (char*)d_ws;
    size_t off = 0;
    auto alloc = [&](size_t bytes) -> char* {
        char* p = ws + off;
        off += (bytes + 255) & ~(size_t)255;
        return p;
    };
    const size_t xelems = (size_t)MROWS * CDIM;       // 12,582,912
    const size_t welems = (size_t)CDIM * CDIM;        // 589,824

    // contiguous bf16 block: [xq16 | xkv16 | Wq | Wk | Wv | Wp]
    unsigned short* cvt16 = (unsigned short*)alloc((2 * xelems + 4 * welems) * 2);
    unsigned short* xq16  = cvt16;
    unsigned short* xkv16 = cvt16 + xelems;
    unsigned short* w16   = cvt16 + 2 * xelems;       // Wq at offset 0
    unsigned short* wp16  = w16 + 3 * welems;

    unsigned short* qphi   = (unsigned short*)alloc(xelems * 2);
    unsigned short* kphi   = (unsigned short*)alloc(xelems * 2);
    unsigned short* v16    = (unsigned short*)alloc(xelems * 2);
    unsigned short* attn16 = (unsigned short*)alloc(xelems * 2);
    float* part = (float*)alloc((size_t)NCHUNK * 48 * 4160 * 4);
    float* kvf  = (float*)alloc((size_t)48 * 4160 * 4);

    // one fused convert: 6,881,280 float4 groups
    cvt_multi<<<26880, 256, 0, stream>>>(x_q, x_kv, Wq, Wk, Wv, Wp, cvt16);

    // fused Q|K|V projections: 2304 blocks
    gemm_t14<0><<<2304, 256, 0, stream>>>(
        xq16, xkv16, w16, bq, bk, bv, qphi, kphi, v16, nullptr);

    kv_part<<<dim3(NCHUNK, 48), 256, 0, stream>>>(kphi, v16, part);
    kv_finalize<<<(48 * 4160 + 255) / 256, 256, 0, stream>>>(part, kvf);
    attn_apply<<<dim3(MROWS / 64, HEADS), 256, 0, stream>>>(qphi, kvf, attn16);

    // output projection -> fp32: 768 blocks
    gemm_t14<1><<<768, 256, 0, stream>>>(
        attn16, nullptr, wp16, bp, nullptr, nullptr,
        nullptr, nullptr, nullptr, out);
}

// Round 7
// 222.953 us; speedup vs baseline: 1.9781x; 1.9781x over previous
//
#include <hip/hip_runtime.h>
#include <hip/hip_bf16.h>
#include <cstdint>
#include <cstddef>

#define HD_B   4
#define SEQ    4096
#define CDIM   768
#define HEADS  12
#define HDIM   64
#define MROWS  (HD_B * SEQ)     // 16384
#define QSCALE 0.125f
#define EPSV   1e-6f

typedef __attribute__((ext_vector_type(8))) short  short8v;  // 8 x bf16
typedef __attribute__((ext_vector_type(4))) float  f32x4;

__device__ __forceinline__ unsigned short f2b(float f) {
    unsigned int u = __float_as_uint(f);
    u += 0x7FFFu + ((u >> 16) & 1u);   // RNE
    return (unsigned short)(u >> 16);
}
__device__ __forceinline__ float b2f(unsigned short b) {
    return __uint_as_float(((unsigned int)b) << 16);
}
__device__ __forceinline__ float phi_f(float x) {  // elu(x)+1
    return x > 0.f ? x + 1.f : __expf(x);
}

#define GLOAD_LDS16(g, l)                                             \
    __builtin_amdgcn_global_load_lds(                                 \
        (__attribute__((address_space(1))) void*)(void*)(g),          \
        (__attribute__((address_space(3))) void*)(l), 16, 0, 0)

#define VMW12() asm volatile("s_waitcnt vmcnt(12)" ::: "memory")
#define VMW8()  asm volatile("s_waitcnt vmcnt(8)"  ::: "memory")
#define VMW4()  asm volatile("s_waitcnt vmcnt(4)"  ::: "memory")
#define VMW0()  asm volatile("s_waitcnt vmcnt(0)"  ::: "memory")
#define LGW()   asm volatile("s_waitcnt lgkmcnt(0)" ::: "memory")
#define SB()    do { __builtin_amdgcn_sched_barrier(0);               \
                     __builtin_amdgcn_s_barrier();                    \
                     __builtin_amdgcn_sched_barrier(0); } while (0)

// ---------------------------------------------------------------- weight cvt
// dst contiguous: [Wq | Wk | Wv | Wp]
__global__ void wcvt_all(const float* __restrict__ wq, const float* __restrict__ wk,
                         const float* __restrict__ wv, const float* __restrict__ wp,
                         unsigned short* __restrict__ dst) {
    const int y = blockIdx.y;
    const float* src = (y == 0) ? wq : (y == 1) ? wk : (y == 2) ? wv : wp;
    const int i = blockIdx.x * 256 + threadIdx.x;
    float4 v = reinterpret_cast<const float4*>(src)[i];
    ushort4 o;
    o.x = f2b(v.x); o.y = f2b(v.y); o.z = f2b(v.z); o.w = f2b(v.w);
    reinterpret_cast<ushort4*>(dst + (size_t)y * (CDIM * CDIM))[i] = o;
}

// ---------------------------------------------------------------- counted-vmcnt GEMM
// 128x128 tile, BK=64, 2 LDS buffers (64 KB), stage-ahead-1, vmcnt never 0 mid-loop.
// KIND 0: fused Q|K|V projections, 2304 blocks (18 col-panels x 128 row-panels), A fp32.
//         mode = colp/6: 0 -> A=x_q, B=Wq, out_q = phi(QSCALE*(acc+b0))
//                        1 -> A=x_kv,B=Wk, out_k = phi(acc+b1)
//                        2 -> A=x_kv,B=Wv, out_v = acc+b2
// KIND 1: output projection, 768 blocks, A=attn16 (bf16, gload_lds), out_f = acc+b0 fp32
template <int KIND>
__global__ __launch_bounds__(256) void gemm_cnt(
    const float* __restrict__ Aq,
    const float* __restrict__ Akv,
    const unsigned short* __restrict__ Abf,
    const unsigned short* __restrict__ Wb,
    const float* __restrict__ b0, const float* __restrict__ b1,
    const float* __restrict__ b2,
    unsigned short* __restrict__ out_q, unsigned short* __restrict__ out_k,
    unsigned short* __restrict__ out_v, float* __restrict__ out_f)
{
    constexpr int K  = CDIM;                 // 768
    constexpr int NC = (KIND == 0) ? 18 : 6;
    constexpr int T  = NC * 128;
    constexpr int NT = K / 64;               // 12

    __shared__ __align__(16) char smem[65536];
    // As buffers at 0 / 16384 ; Bs buffers at 32768 / 49152

    const int tid  = threadIdx.x;
    const int lane = tid & 63;
    const int w    = tid >> 6;
    const int wr   = w >> 1, wc = w & 1;

    // bijective XCD swizzle (T % 8 == 0), cols fast within each XCD band
    const int bid  = blockIdx.x;
    const int s    = (bid & 7) * (T >> 3) + (bid >> 3);
    const int colp = s % NC;
    const int rowp = s / NC;
    const int brow = rowp * 128;
    const int mode = (KIND == 0) ? (colp / 6) : 3;
    const int bcol = (KIND == 0) ? (colp % 6) * 128 : colp * 128;

    const float* A32          = (KIND == 0) ? (mode == 0 ? Aq : Akv) : nullptr;
    const unsigned short* Bp  = Wb + ((KIND == 0) ? (size_t)mode * (K * K) : 0);

    // gload_lds staging geometry (pre-swizzled source, linear dest)
    const int r8  = lane >> 3;                 // 0..7
    const int c8e = ((lane & 7) ^ r8) << 3;    // pre-swizzled element col
    // fp32 reg staging geometry
    const int ar  = lane >> 4;                 // 0..3 (4 rows / inst)
    const int ac  = (lane & 15) << 2;          // fp32 col 0..60
    // frag-read geometry
    const int fr  = lane & 15;
    const int hi4 = lane >> 4;

    f32x4 acc[4][4];
#pragma unroll
    for (int i = 0; i < 4; ++i)
#pragma unroll
        for (int j = 0; j < 4; ++j)
            acc[i][j] = (f32x4){0.f, 0.f, 0.f, 0.f};

    auto stageB = [&](int buf, int kt) {
        char* dst = smem + 32768 + buf * 16384;
#pragma unroll
        for (int g = 0; g < 4; ++g) {
            const unsigned short* src =
                Bp + (size_t)(bcol + w * 32 + g * 8 + r8) * K + kt * 64 + c8e;
            GLOAD_LDS16(src, dst + (w * 32 + g * 8) * 128);
        }
    };
    auto stageA16 = [&](int buf, int kt) {
        char* dst = smem + buf * 16384;
#pragma unroll
        for (int g = 0; g < 4; ++g) {
            const unsigned short* src =
                Abf + (size_t)(brow + w * 32 + g * 8 + r8) * K + kt * 64 + c8e;
            GLOAD_LDS16(src, dst + (w * 32 + g * 8) * 128);
        }
    };
    float4 fA[8];
    auto aload = [&](int kt) {
#pragma unroll
        for (int j = 0; j < 8; ++j)
            fA[j] = *(const float4*)(A32 + (size_t)(brow + w * 32 + j * 4 + ar) * K
                                     + kt * 64 + ac);
    };
    auto awrite = [&](int buf) {
        char* dst = smem + buf * 16384;
#pragma unroll
        for (int j = 0; j < 8; ++j) {
            const int row = w * 32 + j * 4 + ar;
            unsigned int p0, p1;
            asm("v_cvt_pk_bf16_f32 %0, %1, %2" : "=v"(p0) : "v"(fA[j].x), "v"(fA[j].y));
            asm("v_cvt_pk_bf16_f32 %0, %1, %2" : "=v"(p1) : "v"(fA[j].z), "v"(fA[j].w));
            uint2 pk; pk.x = p0; pk.y = p1;
            *(uint2*)(dst + row * 128 + ((ac << 1) ^ ((row & 7) << 4))) = pk;
        }
    };
    auto compute = [&](int buf) {
        const char* Ab = smem + buf * 16384;
        const char* Bb = smem + 32768 + buf * 16384;
        short8v a[4][2];
#pragma unroll
        for (int i = 0; i < 4; ++i) {
            const int row = wr * 64 + i * 16 + fr;
#pragma unroll
            for (int ks = 0; ks < 2; ++ks)
                a[i][ks] = *(const short8v*)(Ab + row * 128 +
                              ((((ks << 2) + hi4) ^ (row & 7)) << 4));
        }
#pragma unroll
        for (int j = 0; j < 4; ++j) {
            const int row = wc * 64 + j * 16 + fr;
            short8v bb0 = *(const short8v*)(Bb + row * 128 + ((hi4 ^ (row & 7)) << 4));
            short8v bb1 = *(const short8v*)(Bb + row * 128 + (((4 + hi4) ^ (row & 7)) << 4));
#pragma unroll
            for (int i = 0; i < 4; ++i) {
                acc[i][j] = __builtin_amdgcn_mfma_f32_16x16x32_bf16(a[i][0], bb0, acc[i][j], 0, 0, 0);
                acc[i][j] = __builtin_amdgcn_mfma_f32_16x16x32_bf16(a[i][1], bb1, acc[i][j], 0, 0, 0);
            }
        }
    };

    if (KIND == 0) {
        // prologue: tile0 A+B, tile1 A+B issued; only A(0) waited.
        aload(0);                 // [A8(0)]
        stageB(0, 0);             // [A8(0), B4(0)]
        VMW4();                   // A8(0) done
        awrite(0);
        aload(1);                 // [B4(0), A8(1)]
        stageB(1, 1);             // [B4(0), A8(1), B4(1)]
        LGW();                    // A(0) ds_writes committed
        SB();
        for (int t = 0; t < NT; ++t) {
            const int c = t & 1;
            if (t == NT - 1) { VMW0(); } else { VMW12(); }   // tile t's B landed
            SB();
            compute(c);
            SB();
            if (t < NT - 1) {
                VMW4();                    // A8(t+1) done (had full compute to land)
                awrite(c ^ 1);
                if (t < NT - 2) { aload(t + 2); stageB(c, t + 2); }  // tile t+2 -> buf c
                LGW();                     // A(t+1) ds_writes committed before next SB
            }
        }
    } else {
        stageA16(0, 0); stageB(0, 0);      // 8
        stageA16(1, 1); stageB(1, 1);      // 16
        for (int t = 0; t < NT; ++t) {
            const int c = t & 1;
            if (t == NT - 1) { VMW0(); } else { VMW8(); }    // tile t's 8 landed
            SB();
            compute(c);
            SB();
            if (t < NT - 2) { stageA16(c, t + 2); stageB(c, t + 2); }  // tile t+2 -> buf c
        }
    }

    // ---------------- epilogue: wave-private LDS transpose, vectorized stores
    float* ep = (float*)(void*)smem + w * (16 * 68);
    const int rr = lane >> 2;
    const int cb = (lane & 3) * 4;
    const float* bptr = (KIND == 1) ? b0 : (mode == 0 ? b0 : (mode == 1 ? b1 : b2));
    unsigned short* o16 = (KIND == 0)
        ? (mode == 0 ? out_q : (mode == 1 ? out_k : out_v)) : nullptr;

    float4 bb[4];
#pragma unroll
    for (int q = 0; q < 4; ++q)
        bb[q] = *(const float4*)&bptr[bcol + wc * 64 + q * 16 + cb];

#pragma unroll
    for (int i = 0; i < 4; ++i) {
#pragma unroll
        for (int j = 0; j < 4; ++j)
#pragma unroll
            for (int r = 0; r < 4; ++r)
                ep[(hi4 * 4 + r) * 68 + j * 16 + fr] = acc[i][j][r];
#pragma unroll
        for (int q = 0; q < 4; ++q) {
            const int cc = q * 16 + cb;
            f32x4 v = *(const f32x4*)&ep[rr * 68 + cc];
            const int rg = brow + wr * 64 + i * 16 + rr;
            const int cg = bcol + wc * 64 + cc;
            const float4 bq = bb[q];
            if (KIND == 1) {
                float4 ov;
                ov.x = v[0] + bq.x; ov.y = v[1] + bq.y;
                ov.z = v[2] + bq.z; ov.w = v[3] + bq.w;
                *(float4*)(out_f + (size_t)rg * 768 + cg) = ov;
            } else {
                ushort4 ov;
                if (mode == 0) {
                    ov.x = f2b(phi_f((v[0] + bq.x) * QSCALE));
                    ov.y = f2b(phi_f((v[1] + bq.y) * QSCALE));
                    ov.z = f2b(phi_f((v[2] + bq.z) * QSCALE));
                    ov.w = f2b(phi_f((v[3] + bq.w) * QSCALE));
                } else if (mode == 1) {
                    ov.x = f2b(phi_f(v[0] + bq.x));
                    ov.y = f2b(phi_f(v[1] + bq.y));
                    ov.z = f2b(phi_f(v[2] + bq.z));
                    ov.w = f2b(phi_f(v[3] + bq.w));
                } else {
                    ov.x = f2b(v[0] + bq.x);
                    ov.y = f2b(v[1] + bq.y);
                    ov.z = f2b(v[2] + bq.z);
                    ov.w = f2b(v[3] + bq.w);
                }
                *(ushort4*)(o16 + (size_t)rg * 768 + cg) = ov;
            }
        }
    }
}

// ---------------------------------------------------------------- KV state
#define KVCH   128
#define KVITER 2
#define NCHUNK 16   // SEQ / (KVCH*KVITER)

__global__ __launch_bounds__(256) void kv_part(
    const unsigned short* __restrict__ kphi,
    const unsigned short* __restrict__ vmat,
    float* __restrict__ part)
{
    const int bh = blockIdx.y;
    const int b  = bh / HEADS, h = bh % HEADS;
    const int c  = blockIdx.x;
    __shared__ float Kl[KVCH][HDIM];
    __shared__ float Vl[KVCH][HDIM];
    const int t  = threadIdx.x;
    const int i  = t >> 2;
    const int jb = t & 3;

    float acc[16];
#pragma unroll
    for (int jj = 0; jj < 16; ++jj) acc[jj] = 0.f;
    float ksum = 0.f;

    for (int it = 0; it < KVITER; ++it) {
        const size_t rbase = (size_t)b * SEQ + (size_t)c * (KVCH * KVITER) + it * KVCH;
        __syncthreads();
        for (int l = 0; l < KVCH / 32; ++l) {
            int row = l * 32 + (t >> 3);
            int col = (t & 7) << 3;
            const size_t g = (rbase + row) * CDIM + h * HDIM + col;
            int4 kk = *(const int4*)(kphi + g);
            int4 vv = *(const int4*)(vmat + g);
            const unsigned short* kp = (const unsigned short*)&kk;
            const unsigned short* vp = (const unsigned short*)&vv;
#pragma unroll
            for (int q = 0; q < 8; ++q) {
                Kl[row][col + q] = b2f(kp[q]);
                Vl[row][col + q] = b2f(vp[q]);
            }
        }
        __syncthreads();
        for (int n = 0; n < KVCH; ++n) {
            float kf = Kl[n][i];
            const float4* vr = (const float4*)&Vl[n][jb * 16];
            float4 v0 = vr[0], v1 = vr[1], v2 = vr[2], v3 = vr[3];
            acc[0]  += kf * v0.x; acc[1]  += kf * v0.y; acc[2]  += kf * v0.z; acc[3]  += kf * v0.w;
            acc[4]  += kf * v1.x; acc[5]  += kf * v1.y; acc[6]  += kf * v1.z; acc[7]  += kf * v1.w;
            acc[8]  += kf * v2.x; acc[9]  += kf * v2.y; acc[10] += kf * v2.z; acc[11] += kf * v2.w;
            acc[12] += kf * v3.x; acc[13] += kf * v3.y; acc[14] += kf * v3.z; acc[15] += kf * v3.w;
            ksum += kf;
        }
    }
    float* op = part + ((size_t)c * 48 + bh) * 4160;
#pragma unroll
    for (int jj = 0; jj < 16; ++jj) op[i * 64 + jb * 16 + jj] = acc[jj];
    if (jb == 0) op[4096 + i] = ksum;
}

__global__ void kv_finalize(const float* __restrict__ part, float* __restrict__ kv) {
    int idx = blockIdx.x * 256 + threadIdx.x;
    if (idx >= 48 * 4160) return;
    float s = 0.f;
    for (int c = 0; c < NCHUNK; ++c) s += part[(size_t)c * 48 * 4160 + idx];
    kv[idx] = s;
}

// ---------------------------------------------------------------- apply
__global__ __launch_bounds__(256) void attn_apply(
    const unsigned short* __restrict__ qphi,
    const float* __restrict__ kv,
    unsigned short* __restrict__ attn)
{
    const int h  = blockIdx.y;
    const int m0 = blockIdx.x * 64;
    const int b  = m0 >> 12;
    const int bh = b * HEADS + h;
    __shared__ float kvs[HDIM][HDIM];
    __shared__ float ksums[HDIM];
    __shared__ unsigned short ql[64][HDIM];
    const int t = threadIdx.x;
    const float* kvp = kv + (size_t)bh * 4160;
#pragma unroll
    for (int it = 0; it < 4; ++it) {
        int e = it * 1024 + t * 4;
        *(float4*)&kvs[e >> 6][e & 63] = *(const float4*)&kvp[e];
    }
    if (t < 64) ksums[t] = kvp[4096 + t];
#pragma unroll
    for (int it = 0; it < 2; ++it) {
        int row = it * 32 + (t >> 3);
        int col = (t & 7) << 3;
        *(int4*)&ql[row][col] =
            *(const int4*)(qphi + (size_t)(m0 + row) * CDIM + h * HDIM + col);
    }
    __syncthreads();

    const int r  = t >> 2;
    const int jb = t & 3;
    float acc[16];
#pragma unroll
    for (int jj = 0; jj < 16; ++jj) acc[jj] = 0.f;
    float z = 0.f;
    for (int q8 = 0; q8 < 8; ++q8) {
        short8v qv = *(const short8v*)&ql[r][q8 * 8];
#pragma unroll
        for (int dd = 0; dd < 8; ++dd) {
            float qd = b2f((unsigned short)qv[dd]);
            int d = q8 * 8 + dd;
            const float4* kr = (const float4*)&kvs[d][jb * 16];
            float4 k0 = kr[0], k1 = kr[1], k2 = kr[2], k3 = kr[3];
            acc[0]  += qd * k0.x; acc[1]  += qd * k0.y; acc[2]  += qd * k0.z; acc[3]  += qd * k0.w;
            acc[4]  += qd * k1.x; acc[5]  += qd * k1.y; acc[6]  += qd * k1.z; acc[7]  += qd * k1.w;
            acc[8]  += qd * k2.x; acc[9]  += qd * k2.y; acc[10] += qd * k2.z; acc[11] += qd * k2.w;
            acc[12] += qd * k3.x; acc[13] += qd * k3.y; acc[14] += qd * k3.z; acc[15] += qd * k3.w;
            z += qd * ksums[d];
        }
    }
    const float inv = 1.f / (z + EPSV);
    unsigned short* op = attn + (size_t)(m0 + r) * CDIM + h * HDIM + jb * 16;
#pragma unroll
    for (int jj = 0; jj < 16; ++jj) op[jj] = f2b(acc[jj] * inv);
}

// ---------------------------------------------------------------- launch
extern "C" void kernel_launch(void* const* d_in, const int* in_sizes, int n_in,
                              void* d_out, int out_size, void* d_ws, size_t ws_size,
                              hipStream_t stream)
{
    const float* x_q  = (const float*)d_in[0];
    const float* x_kv = (const float*)d_in[1];
    const float* Wq   = (const float*)d_in[2];
    const float* bq   = (const float*)d_in[3];
    const float* Wk   = (const float*)d_in[4];
    const float* bk   = (const float*)d_in[5];
    const float* Wv   = (const float*)d_in[6];
    const float* bv   = (const float*)d_in[7];
    const float* Wp   = (const float*)d_in[8];
    const float* bp   = (const float*)d_in[9];
    float* out = (float*)d_out;

    char* ws = (char*)d_ws;
    size_t off = 0;
    auto alloc = [&](size_t bytes) -> char* {
        char* p = ws + off;
        off += (bytes + 255) & ~(size_t)255;
        return p;
    };
    const size_t xelems = (size_t)MROWS * CDIM;
    const size_t welems = (size_t)CDIM * CDIM;

    // weights contiguous: [Wq, Wk, Wv, Wp]
    unsigned short* w16    = (unsigned short*)alloc(4 * welems * 2);
    unsigned short* wp16   = w16 + 3 * welems;
    unsigned short* qphi   = (unsigned short*)alloc(xelems * 2);
    unsigned short* kphi   = (unsigned short*)alloc(xelems * 2);
    unsigned short* v16    = (unsigned short*)alloc(xelems * 2);
    unsigned short* attn16 = (unsigned short*)alloc(xelems * 2);
    float* part = (float*)alloc((size_t)NCHUNK * 48 * 4160 * 4);
    float* kvf  = (float*)alloc((size_t)48 * 4160 * 4);

    wcvt_all<<<dim3(576, 4), 256, 0, stream>>>(Wq, Wk, Wv, Wp, w16);

    // fused Q|K|V projections (fp32 A): 2304 blocks
    gemm_cnt<0><<<2304, 256, 0, stream>>>(
        x_q, x_kv, nullptr, w16, bq, bk, bv, qphi, kphi, v16, nullptr);

    kv_part<<<dim3(NCHUNK, 48), 256, 0, stream>>>(kphi, v16, part);
    kv_finalize<<<(48 * 4160 + 255) / 256, 256, 0, stream>>>(part, kvf);
    attn_apply<<<dim3(MROWS / 64, HEADS), 256, 0, stream>>>(qphi, kvf, attn16);

    // output projection (bf16 A) -> fp32: 768 blocks
    gemm_cnt<1><<<768, 256, 0, stream>>>(
        nullptr, nullptr, attn16, wp16, bp, nullptr, nullptr,
        nullptr, nullptr, nullptr, out);
}